// Round 3
// baseline (335516.211 us; speedup 1.0000x reference)
//
#include <hip/hip_runtime.h>
#include <hip/hip_fp16.h>

// Problem: unbatched GRU scanned over batch-flattened sequence.
//   Encoder: 30720 serial steps, Decoder: 3840 serial steps (independent chains).
//   Per step: gh = W_hh (768x256) . h (256)  -- serial in h.
// Strategy:
//   K1: precompute gi = x @ W_ih^T + b_ih for all rows (parallel GEMM) -> ws as f16.
//   K2: 2 blocks (enc, dec), 768 threads each; W_hh row-resident in VGPRs as half2;
//       h broadcast via LDS; v_dot2_f32_f16 inner product; 2 barriers/step.
//
// R1: VGPR_Count=84 -> compiler rematerialized W_hh global loads into the loop
//     (FETCH_SIZE 27.4GB == 786KB/step arithmetic).
// R2: __launch_bounds__(768,3) was a no-op (VGPR still 84, FETCH unchanged):
//     min-waves only caps VGPRs, doesn't stop remat-for-occupancy.
// R3 fix: (a) amdgpu_waves_per_eu(3,3) -- max=3 sets scheduler occupancy TARGET
//     to 3 waves/EU (budget 168); (b) opaque-asm pin on each weight reg makes
//     rematerialization illegal; (c) unroll 4 keeps live hv temps ~16 so the
//     pinned 128 weight regs + working set stay under 168.

typedef _Float16 h2 __attribute__((ext_vector_type(2)));
typedef _Float16 h4 __attribute__((ext_vector_type(4)));

union HU { unsigned int u; h2 v; };

__device__ __forceinline__ h2 as_h2(unsigned int u) { HU x; x.u = u; return x.v; }

__device__ __forceinline__ float fdot2(h2 a, h2 b, float c) {
#if __has_builtin(__builtin_amdgcn_fdot2)
  return __builtin_amdgcn_fdot2(a, b, c, false);
#else
  return c + (float)a[0] * (float)b[0] + (float)a[1] * (float)b[1];
#endif
}

__device__ __forceinline__ float fast_sigmoid(float x) {
  return __builtin_amdgcn_rcpf(1.0f + __builtin_amdgcn_exp2f(x * -1.4426950408889634f));
}

constexpr int B = 128, T_IN = 240, T_OUT = 30, D = 128, H = 256, G = 768; // G = 3H
constexpr int L_ENC = B * T_IN;   // 30720
constexpr int L_DEC = B * T_OUT;  // 3840
// workspace need: (L_ENC + L_DEC) * G * sizeof(_Float16) = 53,084,160 bytes

// ---------------- K1: gi = x @ W_ih^T + b_ih (both enc and dec segments) ----
__global__ __launch_bounds__(256) void gi_gemm(
    const float* __restrict__ x,
    const float* __restrict__ Wih_e, const float* __restrict__ bih_e,
    const float* __restrict__ Wih_d, const float* __restrict__ bih_d,
    _Float16* __restrict__ gi)
{
  const int jt = blockIdx.x;            // 0..11
  const int by = blockIdx.y;            // 0..539
  const bool enc = by < (L_ENC / 64);
  const int row0 = enc ? by * 64 : (by - L_ENC / 64) * 64;  // segment-local
  const float* __restrict__ W  = enc ? Wih_e : Wih_d;
  const float* __restrict__ bi = enc ? bih_e : bih_d;
  _Float16* __restrict__ gout = enc ? gi : gi + (size_t)L_ENC * G;

  __shared__ float xs[64][132];   // +4 pad
  __shared__ float ws[64][132];
  const int t = threadIdx.x;
#pragma unroll
  for (int p = 0; p < 8; ++p) {
    int idx = p * 256 + t;
    int r  = idx >> 5;
    int c4 = (idx & 31) * 4;
    int i  = row0 + r;
    int bb = i & (B - 1);
    int tt = i >> 7;
    if (!enc) tt *= 8;            // decoder reads x[:, ::8, :]
    float4 xv = *(const float4*)(x + (size_t)(bb * T_IN + tt) * D + c4);
    *(float4*)&xs[r][c4] = xv;
    float4 wv = *(const float4*)(W + (size_t)(jt * 64 + r) * D + c4);
    *(float4*)&ws[r][c4] = wv;
  }
  __syncthreads();

  const int tr = t >> 4, tc = t & 15;
  float acc[4][4] = {};
  for (int k4 = 0; k4 < 128; k4 += 4) {
    float4 xa[4], wa[4];
#pragma unroll
    for (int q = 0; q < 4; ++q) xa[q] = *(const float4*)&xs[tr * 4 + q][k4];
#pragma unroll
    for (int q = 0; q < 4; ++q) wa[q] = *(const float4*)&ws[tc * 4 + q][k4];
#pragma unroll
    for (int r = 0; r < 4; ++r)
#pragma unroll
      for (int c = 0; c < 4; ++c)
        acc[r][c] += xa[r].x * wa[c].x + xa[r].y * wa[c].y +
                     xa[r].z * wa[c].z + xa[r].w * wa[c].w;
  }

  const int col = jt * 64 + tc * 4;
  float bv[4];
#pragma unroll
  for (int c = 0; c < 4; ++c) bv[c] = bi[col + c];
#pragma unroll
  for (int r = 0; r < 4; ++r) {
    int grow = row0 + tr * 4 + r;
    h4 o;
#pragma unroll
    for (int c = 0; c < 4; ++c) o[c] = (_Float16)(acc[r][c] + bv[c]);
    *(h4*)(gout + (size_t)grow * G + col) = o;
  }
}

// ---------------- K2: serial GRU scan --------------------------------------
// block 0 = encoder (30720 steps), block 1 = decoder (3840 steps).
// 768 threads = 12 waves; thread tid owns W_hh row tid as 128 pinned uint regs.
__global__ __launch_bounds__(768)
__attribute__((amdgpu_waves_per_eu(3, 3)))
void gru_serial(
    const _Float16* __restrict__ gi,
    const float* __restrict__ Whh_e, const float* __restrict__ bhh_e,
    const float* __restrict__ Whh_d, const float* __restrict__ bhh_d,
    float* __restrict__ out)
{
  const int tid = threadIdx.x;
  const bool enc = (blockIdx.x == 0);
  const int L = enc ? L_ENC : L_DEC;
  const float* __restrict__ W  = enc ? Whh_e : Whh_d;
  const float* __restrict__ bh = enc ? bhh_e : bhh_d;
  const _Float16* __restrict__ gbase = enc ? gi : gi + (size_t)L_ENC * G;
  float* __restrict__ obase = enc ? out : out + T_IN * H;

  __shared__ __align__(16) unsigned int h_lds[H / 2]; // 256 f16 as 128 uints
  __shared__ float gh_lds[G];
  __shared__ float gin_lds[H];

  // Load W_hh row tid -> 128 uint regs (h2 pairs), then PIN with opaque asm so
  // the compiler cannot rematerialize the global loads inside the step loop.
  unsigned int wu[128];
  {
    const float4* wr = (const float4*)(W + (size_t)tid * H);
#pragma unroll
    for (int c = 0; c < 64; ++c) {
      float4 f = wr[c];
      HU a; a.v[0] = (_Float16)f.x; a.v[1] = (_Float16)f.y;
      HU b; b.v[0] = (_Float16)f.z; b.v[1] = (_Float16)f.w;
      wu[2 * c]     = a.u;
      wu[2 * c + 1] = b.u;
    }
  }
#pragma unroll
  for (int c = 0; c < 128; ++c) asm volatile("" : "+v"(wu[c]));

  const float bhh_r = bh[tid];
  if (tid < H / 2) h_lds[tid] = 0u;   // h0 = 0
  float h_old = 0.0f;
  __syncthreads();

  float gnext = (float)gbase[tid];    // prefetch gi[0][tid]
  for (int i = 0; i < L; ++i) {
    const float gcur = gnext;
    {
      int inext = (i + 1 < L) ? (i + 1) : i;
      gnext = (float)gbase[(size_t)inext * G + tid];
    }
    // gh[tid] = dot(W_hh[tid,:], h); unroll 4 keeps ~16 hv temps live.
    float a0 = 0.f, a1 = 0.f, a2 = 0.f, a3 = 0.f;
    const uint4* hp = (const uint4*)h_lds;
#pragma unroll 4
    for (int c = 0; c < 32; ++c) {
      uint4 hv = hp[c];               // ds_read_b128 broadcast
      a0 = fdot2(as_h2(wu[4 * c + 0]), as_h2(hv.x), a0);
      a1 = fdot2(as_h2(wu[4 * c + 1]), as_h2(hv.y), a1);
      a2 = fdot2(as_h2(wu[4 * c + 2]), as_h2(hv.z), a2);
      a3 = fdot2(as_h2(wu[4 * c + 3]), as_h2(hv.w), a3);
    }
    const float acc = ((a0 + a1) + (a2 + a3)) + bhh_r;
    if (tid < 2 * H) {
      gh_lds[tid] = acc + gcur;       // r,z rows: fold gi in
    } else {
      gh_lds[tid] = acc;              // n row: h-part separate
      gin_lds[tid - 2 * H] = gcur;
    }
    __syncthreads();

    if (tid < H) {
      const float pr = gh_lds[tid];
      const float pz = gh_lds[H + tid];
      const float hn = gh_lds[2 * H + tid];
      const float gn = gin_lds[tid];
      const float r = fast_sigmoid(pr);
      const float z = fast_sigmoid(pz);
      const float n = 2.0f * fast_sigmoid(2.0f * (gn + r * hn)) - 1.0f; // tanh
      const float hnew = (1.0f - z) * n + z * h_old;
      h_old = hnew;
      ((_Float16*)h_lds)[tid] = (_Float16)hnew;
      if (enc) {
        if ((i & (B - 1)) == (B - 1))
          obase[(i >> 7) * H + tid] = hnew;
      } else {
        obase[((i & (B - 1)) * T_OUT + (i >> 7)) * H + tid] = hnew;
      }
    }
    __syncthreads();
  }
}

extern "C" void kernel_launch(void* const* d_in, const int* in_sizes, int n_in,
                              void* d_out, int out_size, void* d_ws, size_t ws_size,
                              hipStream_t stream) {
  (void)in_sizes; (void)n_in; (void)out_size; (void)ws_size;
  const float* x     = (const float*)d_in[0];
  const float* Wih_e = (const float*)d_in[1];
  const float* Whh_e = (const float*)d_in[2];
  const float* bih_e = (const float*)d_in[3];
  const float* bhh_e = (const float*)d_in[4];
  const float* Wih_d = (const float*)d_in[5];
  const float* Whh_d = (const float*)d_in[6];
  const float* bih_d = (const float*)d_in[7];
  const float* bhh_d = (const float*)d_in[8];
  float* out = (float*)d_out;
  _Float16* gi = (_Float16*)d_ws;    // needs 53,084,160 B

  dim3 g1(12, (L_ENC + L_DEC) / 64);
  gi_gemm<<<g1, 256, 0, stream>>>(x, Wih_e, bih_e, Wih_d, bih_d, gi);
  gru_serial<<<dim3(2), dim3(768), 0, stream>>>(gi, Whh_e, bhh_e, Whh_d, bhh_d, out);
}

// Round 4
// 334186.084 us; speedup vs baseline: 1.0040x; 1.0040x over previous
//
#include <hip/hip_runtime.h>
#include <hip/hip_fp16.h>

// Problem: unbatched GRU scanned over batch-flattened sequence.
//   Encoder: 30720 serial steps, Decoder: 3840 serial steps (independent chains).
//   Per step: gh = W_hh (768x256) . h (256)  -- serial in h.
// Strategy:
//   K1: precompute gi = x @ W_ih^T + b_ih for all rows (parallel GEMM) -> ws as f16.
//   K2: 2 blocks (enc, dec), 768 threads each; W_hh row-resident in VGPRs;
//       h broadcast via LDS; v_dot2_f32_f16 inner product; 2 barriers/step.
//
// R1: VGPR=84, FETCH 27.4GB -> compiler rematerialized W_hh global loads in-loop.
// R2: __launch_bounds__(768,3) no-op (min-waves caps VGPR but doesn't stop remat).
// R3: unroll-4 made wu[] indices dynamic -> array demoted to SCRATCH; asm pins
//     forced scratch round-trips -> 335ms. Lesson: reg-arrays need full unroll.
// R4: launder weights through LDS. ds_read results are NOT rematerializable
//     (LDS non-invariant, buffer rewritten by other threads across barriers),
//     so the allocator must keep them in VGPRs (or visibly spill). Cross-thread
//     write/read (thread t writes row (t+1)%768) kills store-to-load forwarding.
//     waves_per_eu(3,3) sets the pressure target to ~170 regs. Full unroll.

typedef _Float16 h2 __attribute__((ext_vector_type(2)));
typedef _Float16 h4 __attribute__((ext_vector_type(4)));

union HU { unsigned int u; h2 v; };

__device__ __forceinline__ h2 as_h2(unsigned int u) { HU x; x.u = u; return x.v; }

__device__ __forceinline__ float fdot2(h2 a, h2 b, float c) {
#if __has_builtin(__builtin_amdgcn_fdot2)
  return __builtin_amdgcn_fdot2(a, b, c, false);
#else
  return c + (float)a[0] * (float)b[0] + (float)a[1] * (float)b[1];
#endif
}

__device__ __forceinline__ float fast_sigmoid(float x) {
  return __builtin_amdgcn_rcpf(1.0f + __builtin_amdgcn_exp2f(x * -1.4426950408889634f));
}

constexpr int B = 128, T_IN = 240, T_OUT = 30, D = 128, H = 256, G = 768; // G = 3H
constexpr int L_ENC = B * T_IN;   // 30720
constexpr int L_DEC = B * T_OUT;  // 3840
// workspace need: (L_ENC + L_DEC) * G * sizeof(_Float16) = 53,084,160 bytes

// ---------------- K1: gi = x @ W_ih^T + b_ih (both enc and dec segments) ----
__global__ __launch_bounds__(256) void gi_gemm(
    const float* __restrict__ x,
    const float* __restrict__ Wih_e, const float* __restrict__ bih_e,
    const float* __restrict__ Wih_d, const float* __restrict__ bih_d,
    _Float16* __restrict__ gi)
{
  const int jt = blockIdx.x;            // 0..11
  const int by = blockIdx.y;            // 0..539
  const bool enc = by < (L_ENC / 64);
  const int row0 = enc ? by * 64 : (by - L_ENC / 64) * 64;  // segment-local
  const float* __restrict__ W  = enc ? Wih_e : Wih_d;
  const float* __restrict__ bi = enc ? bih_e : bih_d;
  _Float16* __restrict__ gout = enc ? gi : gi + (size_t)L_ENC * G;

  __shared__ float xs[64][132];   // +4 pad
  __shared__ float ws[64][132];
  const int t = threadIdx.x;
#pragma unroll
  for (int p = 0; p < 8; ++p) {
    int idx = p * 256 + t;
    int r  = idx >> 5;
    int c4 = (idx & 31) * 4;
    int i  = row0 + r;
    int bb = i & (B - 1);
    int tt = i >> 7;
    if (!enc) tt *= 8;            // decoder reads x[:, ::8, :]
    float4 xv = *(const float4*)(x + (size_t)(bb * T_IN + tt) * D + c4);
    *(float4*)&xs[r][c4] = xv;
    float4 wv = *(const float4*)(W + (size_t)(jt * 64 + r) * D + c4);
    *(float4*)&ws[r][c4] = wv;
  }
  __syncthreads();

  const int tr = t >> 4, tc = t & 15;
  float acc[4][4] = {};
  for (int k4 = 0; k4 < 128; k4 += 4) {
    float4 xa[4], wa[4];
#pragma unroll
    for (int q = 0; q < 4; ++q) xa[q] = *(const float4*)&xs[tr * 4 + q][k4];
#pragma unroll
    for (int q = 0; q < 4; ++q) wa[q] = *(const float4*)&ws[tc * 4 + q][k4];
#pragma unroll
    for (int r = 0; r < 4; ++r)
#pragma unroll
      for (int c = 0; c < 4; ++c)
        acc[r][c] += xa[r].x * wa[c].x + xa[r].y * wa[c].y +
                     xa[r].z * wa[c].z + xa[r].w * wa[c].w;
  }

  const int col = jt * 64 + tc * 4;
  float bv[4];
#pragma unroll
  for (int c = 0; c < 4; ++c) bv[c] = bi[col + c];
#pragma unroll
  for (int r = 0; r < 4; ++r) {
    int grow = row0 + tr * 4 + r;
    h4 o;
#pragma unroll
    for (int c = 0; c < 4; ++c) o[c] = (_Float16)(acc[r][c] + bv[c]);
    *(h4*)(gout + (size_t)grow * G + col) = o;
  }
}

// ---------------- K2: serial GRU scan --------------------------------------
// block 0 = encoder (30720 steps), block 1 = decoder (3840 steps).
// 768 threads = 12 waves on one CU; thread tid owns W_hh row tid as 32 uint4
// regs, laundered through LDS so the values are un-rematerializable.
__global__ __launch_bounds__(768)
__attribute__((amdgpu_waves_per_eu(3, 3)))
void gru_serial(
    const _Float16* __restrict__ gi,
    const float* __restrict__ Whh_e, const float* __restrict__ bhh_e,
    const float* __restrict__ Whh_d, const float* __restrict__ bhh_d,
    float* __restrict__ out)
{
  const int tid = threadIdx.x;
  const bool enc = (blockIdx.x == 0);
  const int L = enc ? L_ENC : L_DEC;
  const float* __restrict__ W  = enc ? Whh_e : Whh_d;
  const float* __restrict__ bh = enc ? bhh_e : bhh_d;
  const _Float16* __restrict__ gbase = enc ? gi : gi + (size_t)L_ENC * G;
  float* __restrict__ obase = enc ? out : out + T_IN * H;

  __shared__ __align__(16) _Float16 stage[G * 32];     // 49152 B staging
  __shared__ __align__(16) unsigned int h_lds[H / 2];  // 256 f16 as 128 uints
  __shared__ float gh_lds[G];
  __shared__ float gin_lds[H];

  // ---- Stage W_hh row tid into 32 uint4 regs via LDS bounce (8 K-chunks). ----
  // Thread t loads global row rr=(t+1)%768 and writes slot rr; then reads its
  // OWN slot t (written by thread t-1): cross-thread => no fwd, no remat.
  uint4 wq[32];
  {
    const int rr = (tid + 1 == G) ? 0 : tid + 1;
    const float* wrow = W + (size_t)rr * H;
#pragma unroll 1
    for (int c = 0; c < 8; ++c) {
      // 32 floats of row rr, cols [32c, 32c+32) -> 32 f16 -> 4 uint4 in LDS
#pragma unroll
      for (int q = 0; q < 4; ++q) {
        float4 f0 = *(const float4*)(wrow + c * 32 + q * 8);
        float4 f1 = *(const float4*)(wrow + c * 32 + q * 8 + 4);
        HU p0, p1, p2, p3;
        p0.v[0] = (_Float16)f0.x; p0.v[1] = (_Float16)f0.y;
        p1.v[0] = (_Float16)f0.z; p1.v[1] = (_Float16)f0.w;
        p2.v[0] = (_Float16)f1.x; p2.v[1] = (_Float16)f1.y;
        p3.v[0] = (_Float16)f1.z; p3.v[1] = (_Float16)f1.w;
        uint4 pk; pk.x = p0.u; pk.y = p1.u; pk.z = p2.u; pk.w = p3.u;
        ((uint4*)stage)[rr * 4 + q] = pk;
      }
      __syncthreads();
#pragma unroll
      for (int q = 0; q < 4; ++q)
        wq[c * 4 + q] = ((const uint4*)stage)[tid * 4 + q];
      __syncthreads();
    }
  }

  const float bhh_r = bh[tid];
  if (tid < H / 2) h_lds[tid] = 0u;   // h0 = 0
  float h_old = 0.0f;                 // f32 copy of h[tid] for tid < H
  __syncthreads();

  const _Float16* gp = gbase + tid;
  float gnext = (float)gp[0];         // prefetch gi[0][tid]
  for (int i = 0; i < L; ++i) {
    const float gcur = gnext;
    gp += (i + 1 < L) ? G : 0;
    gnext = (float)gp[0];             // latency hidden by matvec

    // gh[tid] = dot(W_hh[tid,:], h); full unroll -> wq[] stays SSA/registers.
    float a0 = 0.f, a1 = 0.f, a2 = 0.f, a3 = 0.f;
    const uint4* hp = (const uint4*)h_lds;
#pragma unroll
    for (int c = 0; c < 32; ++c) {
      uint4 hv = hp[c];               // ds_read_b128, same addr all lanes: broadcast
      a0 = fdot2(as_h2(wq[c].x), as_h2(hv.x), a0);
      a1 = fdot2(as_h2(wq[c].y), as_h2(hv.y), a1);
      a2 = fdot2(as_h2(wq[c].z), as_h2(hv.z), a2);
      a3 = fdot2(as_h2(wq[c].w), as_h2(hv.w), a3);
    }
    const float acc = ((a0 + a1) + (a2 + a3)) + bhh_r;
    if (tid < 2 * H) {
      gh_lds[tid] = acc + gcur;       // r,z rows: fold gi in
    } else {
      gh_lds[tid] = acc;              // n row: h-part separate
      gin_lds[tid - 2 * H] = gcur;
    }
    __syncthreads();

    if (tid < H) {
      const float pr = gh_lds[tid];
      const float pz = gh_lds[H + tid];
      const float hn = gh_lds[2 * H + tid];
      const float gn = gin_lds[tid];
      const float r = fast_sigmoid(pr);
      const float z = fast_sigmoid(pz);
      const float n = 2.0f * fast_sigmoid(2.0f * (gn + r * hn)) - 1.0f; // tanh
      const float hnew = (1.0f - z) * n + z * h_old;
      h_old = hnew;
      ((_Float16*)h_lds)[tid] = (_Float16)hnew;
      if (enc) {
        if ((i & (B - 1)) == (B - 1))             // every 128th step
          obase[(i >> 7) * H + tid] = hnew;
      } else {
        obase[((i & (B - 1)) * T_OUT + (i >> 7)) * H + tid] = hnew;
      }
    }
    __syncthreads();
  }
}

extern "C" void kernel_launch(void* const* d_in, const int* in_sizes, int n_in,
                              void* d_out, int out_size, void* d_ws, size_t ws_size,
                              hipStream_t stream) {
  (void)in_sizes; (void)n_in; (void)out_size; (void)ws_size;
  const float* x     = (const float*)d_in[0];
  const float* Wih_e = (const float*)d_in[1];
  const float* Whh_e = (const float*)d_in[2];
  const float* bih_e = (const float*)d_in[3];
  const float* bhh_e = (const float*)d_in[4];
  const float* Wih_d = (const float*)d_in[5];
  const float* Whh_d = (const float*)d_in[6];
  const float* bih_d = (const float*)d_in[7];
  const float* bhh_d = (const float*)d_in[8];
  float* out = (float*)d_out;
  _Float16* gi = (_Float16*)d_ws;    // needs 53,084,160 B

  dim3 g1(12, (L_ENC + L_DEC) / 64);
  gi_gemm<<<g1, 256, 0, stream>>>(x, Wih_e, bih_e, Wih_d, bih_d, gi);
  gru_serial<<<dim3(2), dim3(768), 0, stream>>>(gi, Whh_e, bhh_e, Whh_d, bhh_d, out);
}

// Round 5
// 36386.652 us; speedup vs baseline: 9.2209x; 9.1843x over previous
//
#include <hip/hip_runtime.h>
#include <hip/hip_fp16.h>

// Problem: unbatched GRU scanned over batch-flattened sequence.
//   Encoder: 30720 serial steps, Decoder: 3840 serial steps (independent chains).
//   Per step: gh = W_hh (768x256) . h (256)  -- serial in h.
// History:
//   R1: 768thr, w[] SSA but remat-able -> compiler refetched W from global
//       every step (FETCH 27.4GB), VGPR 84. 36.7ms.
//   R2: launch_bounds(768,3) no-op: min-waves caps but doesn't stop remat.
//   R3/R4: my bug -- dynamic indices into w[]/wq[] (partial unroll / unroll-1
//       staging loop) -> array demoted to scratch -> 334ms. LDS-launder never
//       actually tested. Key insight from R4 counters: VGPR 84 == 512/6 ==
//       budget for 6 waves/EU == 2 blocks/CU, which the 53KB LDS allowed.
//   R5: make the VGPR budget rise DETERMINISTICALLY: LDS block > 80KB forces
//       1 block/CU; with 512 threads (8 waves) that's 2 waves/EU -> budget 256.
//       Weights: 3 rows x 128 cols per thread = 48 uint4 = 192 regs, laundered
//       through LDS (un-remat-able) with fully-constant indices (SSA-able).
//       Halves of each row combined via __shfl_xor(32). DS h-broadcast traffic
//       also drops 3x vs R1 (16 b128/thread instead of 32, 8 waves not 12).

typedef _Float16 h2 __attribute__((ext_vector_type(2)));
typedef _Float16 h4 __attribute__((ext_vector_type(4)));

union HU { unsigned int u; h2 v; };

__device__ __forceinline__ h2 as_h2(unsigned int u) { HU x; x.u = u; return x.v; }

__device__ __forceinline__ float fdot2(h2 a, h2 b, float c) {
#if __has_builtin(__builtin_amdgcn_fdot2)
  return __builtin_amdgcn_fdot2(a, b, c, false);
#else
  return c + (float)a[0] * (float)b[0] + (float)a[1] * (float)b[1];
#endif
}

__device__ __forceinline__ float fast_sigmoid(float x) {
  return __builtin_amdgcn_rcpf(1.0f + __builtin_amdgcn_exp2f(x * -1.4426950408889634f));
}

constexpr int B = 128, T_IN = 240, T_OUT = 30, D = 128, H = 256, G = 768; // G = 3H
constexpr int L_ENC = B * T_IN;   // 30720
constexpr int L_DEC = B * T_OUT;  // 3840
// workspace need: (L_ENC + L_DEC) * G * sizeof(_Float16) = 53,084,160 bytes

// ---------------- K1: gi = x @ W_ih^T + b_ih (both enc and dec segments) ----
__global__ __launch_bounds__(256) void gi_gemm(
    const float* __restrict__ x,
    const float* __restrict__ Wih_e, const float* __restrict__ bih_e,
    const float* __restrict__ Wih_d, const float* __restrict__ bih_d,
    _Float16* __restrict__ gi)
{
  const int jt = blockIdx.x;            // 0..11
  const int by = blockIdx.y;            // 0..539
  const bool enc = by < (L_ENC / 64);
  const int row0 = enc ? by * 64 : (by - L_ENC / 64) * 64;  // segment-local
  const float* __restrict__ W  = enc ? Wih_e : Wih_d;
  const float* __restrict__ bi = enc ? bih_e : bih_d;
  _Float16* __restrict__ gout = enc ? gi : gi + (size_t)L_ENC * G;

  __shared__ float xs[64][132];   // +4 pad
  __shared__ float ws[64][132];
  const int t = threadIdx.x;
#pragma unroll
  for (int p = 0; p < 8; ++p) {
    int idx = p * 256 + t;
    int r  = idx >> 5;
    int c4 = (idx & 31) * 4;
    int i  = row0 + r;
    int bb = i & (B - 1);
    int tt = i >> 7;
    if (!enc) tt *= 8;            // decoder reads x[:, ::8, :]
    float4 xv = *(const float4*)(x + (size_t)(bb * T_IN + tt) * D + c4);
    *(float4*)&xs[r][c4] = xv;
    float4 wv = *(const float4*)(W + (size_t)(jt * 64 + r) * D + c4);
    *(float4*)&ws[r][c4] = wv;
  }
  __syncthreads();

  const int tr = t >> 4, tc = t & 15;
  float acc[4][4] = {};
  for (int k4 = 0; k4 < 128; k4 += 4) {
    float4 xa[4], wa[4];
#pragma unroll
    for (int q = 0; q < 4; ++q) xa[q] = *(const float4*)&xs[tr * 4 + q][k4];
#pragma unroll
    for (int q = 0; q < 4; ++q) wa[q] = *(const float4*)&ws[tc * 4 + q][k4];
#pragma unroll
    for (int r = 0; r < 4; ++r)
#pragma unroll
      for (int c = 0; c < 4; ++c)
        acc[r][c] += xa[r].x * wa[c].x + xa[r].y * wa[c].y +
                     xa[r].z * wa[c].z + xa[r].w * wa[c].w;
  }

  const int col = jt * 64 + tc * 4;
  float bv[4];
#pragma unroll
  for (int c = 0; c < 4; ++c) bv[c] = bi[col + c];
#pragma unroll
  for (int r = 0; r < 4; ++r) {
    int grow = row0 + tr * 4 + r;
    h4 o;
#pragma unroll
    for (int c = 0; c < 4; ++c) o[c] = (_Float16)(acc[r][c] + bv[c]);
    *(h4*)(gout + (size_t)grow * G + col) = o;
  }
}

// ---------------- K2: serial GRU scan --------------------------------------
// block 0 = encoder, block 1 = decoder. 512 threads = 8 waves.
// thread: k = wave*32 + (lane&31), hs = lane>>5. Owns rows 3k..3k+2,
// cols [128*hs, 128*hs+128) as wq[48] (uint4 of 8 f16). Partner = lane^32.
constexpr int NT = 512;
constexpr int CHUNK = 12;            // uint4 per thread per staging round
// stage LDS = 512*12*16 = 98304 B > 80KB -> 1 block/CU -> 2 waves/EU ->
// VGPR budget 256. This is the deterministic lever (attrs alone failed R2-R4).

__global__
__attribute__((amdgpu_flat_work_group_size(NT, NT)))
__attribute__((amdgpu_waves_per_eu(2, 2)))
void gru_serial(
    const _Float16* __restrict__ gi,
    const float* __restrict__ Whh_e, const float* __restrict__ bhh_e,
    const float* __restrict__ Whh_d, const float* __restrict__ bhh_d,
    float* __restrict__ out)
{
  const int tid = threadIdx.x;
  const bool enc = (blockIdx.x == 0);
  const int L = enc ? L_ENC : L_DEC;
  const float* __restrict__ W  = enc ? Whh_e : Whh_d;
  const float* __restrict__ bh = enc ? bhh_e : bhh_d;
  const _Float16* __restrict__ gbase = enc ? gi : gi + (size_t)L_ENC * G;
  float* __restrict__ obase = enc ? out : out + T_IN * H;

  __shared__ __align__(16) uint4 stage_q[NT * CHUNK];   // 98304 B
  __shared__ __align__(16) unsigned int h_lds[H / 2];   // 256 f16
  __shared__ float gh_lds[G];                            // W_hh.h + b_hh, per row

  const int lane = tid & 63, wave = tid >> 6;
  const int k  = wave * 32 + (lane & 31);   // 0..255
  const int hs = lane >> 5;                 // column half

  // ---- Stage weights: thread t loads for t' = t+1 (cross-thread, kills
  // forwarding/remat), 4 fully-unrolled chunks; wq[] indices all constant.
  uint4 wq[48];
  {
    const int tp  = (tid + 1) & (NT - 1);
    const int kp  = ((tp >> 6) << 5) + (tp & 31);
    const int hsp = (tp >> 5) & 1;
#pragma unroll
    for (int cch = 0; cch < 4; ++cch) {
#pragma unroll
      for (int j = 0; j < CHUNK; ++j) {
        const int u  = cch * CHUNK + j;     // 0..47, constant
        const int m  = u >> 4;              // row 0..2
        const int ci = u & 15;              // col-16B index
        const float* p = W + (size_t)(3 * kp + m) * H + hsp * 128 + ci * 8;
        float4 f0 = *(const float4*)(p);
        float4 f1 = *(const float4*)(p + 4);
        HU a, b, c2, d;
        a.v[0]  = (_Float16)f0.x; a.v[1]  = (_Float16)f0.y;
        b.v[0]  = (_Float16)f0.z; b.v[1]  = (_Float16)f0.w;
        c2.v[0] = (_Float16)f1.x; c2.v[1] = (_Float16)f1.y;
        d.v[0]  = (_Float16)f1.z; d.v[1]  = (_Float16)f1.w;
        uint4 pk; pk.x = a.u; pk.y = b.u; pk.z = c2.u; pk.w = d.u;
        stage_q[tp * CHUNK + j] = pk;
      }
      __syncthreads();
#pragma unroll
      for (int j = 0; j < CHUNK; ++j)
        wq[cch * CHUNK + j] = stage_q[tid * CHUNK + j];
      __syncthreads();
    }
  }

  // Biases for this thread's 3 rows (used by hs==0 lanes only).
  const float bb0 = bh[3 * k + 0];
  const float bb1 = bh[3 * k + 1];
  const float bb2 = bh[3 * k + 2];

  if (tid < H / 2) h_lds[tid] = 0u;   // h0 = 0
  float h_old = 0.0f;                 // gate threads' f32 h[tid]
  __syncthreads();

  // Gate threads (tid<256) prefetch gi for step 0.
  float g0n = 0.f, g1n = 0.f, g2n = 0.f;
  if (tid < H) {
    g0n = (float)gbase[tid];
    g1n = (float)gbase[H + tid];
    g2n = (float)gbase[2 * H + tid];
  }

  for (int i = 0; i < L; ++i) {
    // ---- matvec: this thread's 3 rows x 128-col half -------------------
    float a0 = 0.f, a1 = 0.f, b0 = 0.f, b1 = 0.f, c0 = 0.f, c1 = 0.f;
    const uint4* hp = (const uint4*)h_lds;
#pragma unroll
    for (int c = 0; c < 16; ++c) {
      uint4 hv = hp[hs * 16 + c];     // 2 distinct addrs/wave: broadcast, free
      a0 = fdot2(as_h2(wq[c].x),      as_h2(hv.x), a0);
      a1 = fdot2(as_h2(wq[c].y),      as_h2(hv.y), a1);
      a0 = fdot2(as_h2(wq[c].z),      as_h2(hv.z), a0);
      a1 = fdot2(as_h2(wq[c].w),      as_h2(hv.w), a1);
      b0 = fdot2(as_h2(wq[16 + c].x), as_h2(hv.x), b0);
      b1 = fdot2(as_h2(wq[16 + c].y), as_h2(hv.y), b1);
      b0 = fdot2(as_h2(wq[16 + c].z), as_h2(hv.z), b0);
      b1 = fdot2(as_h2(wq[16 + c].w), as_h2(hv.w), b1);
      c0 = fdot2(as_h2(wq[32 + c].x), as_h2(hv.x), c0);
      c1 = fdot2(as_h2(wq[32 + c].y), as_h2(hv.y), c1);
      c0 = fdot2(as_h2(wq[32 + c].z), as_h2(hv.z), c0);
      c1 = fdot2(as_h2(wq[32 + c].w), as_h2(hv.w), c1);
    }
    float r0 = a0 + a1, r1 = b0 + b1, r2 = c0 + c1;
    r0 += __shfl_xor(r0, 32);         // combine column halves (partner lane^32)
    r1 += __shfl_xor(r1, 32);
    r2 += __shfl_xor(r2, 32);
    if (hs == 0) {
      gh_lds[3 * k + 0] = r0 + bb0;   // row-indexed: rows 0..255=r, ..z, ..n
      gh_lds[3 * k + 1] = r1 + bb1;
      gh_lds[3 * k + 2] = r2 + bb2;
    }
    __syncthreads();

    // ---- gates (tid < 256) ---------------------------------------------
    if (tid < H) {
      const float gc0 = g0n, gc1 = g1n, gc2 = g2n;
      {
        const size_t nb = (size_t)((i + 1 < L) ? i + 1 : i) * G;
        g0n = (float)gbase[nb + tid];           // prefetch next step's gi
        g1n = (float)gbase[nb + H + tid];
        g2n = (float)gbase[nb + 2 * H + tid];
      }
      const float pr = gh_lds[tid] + gc0;
      const float pz = gh_lds[H + tid] + gc1;
      const float hn = gh_lds[2 * H + tid];     // h-part of n (bias inside)
      const float r = fast_sigmoid(pr);
      const float z = fast_sigmoid(pz);
      const float n = 2.0f * fast_sigmoid(2.0f * (gc2 + r * hn)) - 1.0f; // tanh
      const float hnew = (1.0f - z) * n + z * h_old;
      h_old = hnew;
      ((_Float16*)h_lds)[tid] = (_Float16)hnew;
      if (enc) {
        if ((i & (B - 1)) == (B - 1))           // every 128th step
          obase[(i >> 7) * H + tid] = hnew;
      } else {
        obase[((i & (B - 1)) * T_OUT + (i >> 7)) * H + tid] = hnew;
      }
    }
    __syncthreads();
  }
}

extern "C" void kernel_launch(void* const* d_in, const int* in_sizes, int n_in,
                              void* d_out, int out_size, void* d_ws, size_t ws_size,
                              hipStream_t stream) {
  (void)in_sizes; (void)n_in; (void)out_size; (void)ws_size;
  const float* x     = (const float*)d_in[0];
  const float* Wih_e = (const float*)d_in[1];
  const float* Whh_e = (const float*)d_in[2];
  const float* bih_e = (const float*)d_in[3];
  const float* bhh_e = (const float*)d_in[4];
  const float* Wih_d = (const float*)d_in[5];
  const float* Whh_d = (const float*)d_in[6];
  const float* bih_d = (const float*)d_in[7];
  const float* bhh_d = (const float*)d_in[8];
  float* out = (float*)d_out;
  _Float16* gi = (_Float16*)d_ws;    // needs 53,084,160 B

  dim3 g1(12, (L_ENC + L_DEC) / 64);
  gi_gemm<<<g1, 256, 0, stream>>>(x, Wih_e, bih_e, Wih_d, bih_d, gi);
  gru_serial<<<dim3(2), dim3(512), 0, stream>>>(gi, Whh_e, bhh_e, Whh_d, bhh_d, out);
}